// Round 5
// baseline (801.370 us; speedup 1.0000x reference)
//
#include <hip/hip_runtime.h>
#include <hip/hip_bf16.h>

// Closed-loop NARX on MI355X.
// Grid: 128 blocks x 512 threads (8 waves). Each block owns 16 batch rows
// for all 504 time steps; the recurrence is per-row so blocks never talk.
// W1/W2 bf16 fragments are register-resident; LDS holds only the circular
// x window, circular y history, and the per-step h tile.

typedef short bf16x8 __attribute__((ext_vector_type(8)));  // 8 bf16 bit patterns (4 VGPRs)
typedef float f32x4  __attribute__((ext_vector_type(4)));

#define MFMA16(A,B,C) __builtin_amdgcn_mfma_f32_16x16x32_bf16((A),(B),(C),0,0,0)

constexpr int DT = 512;              // T
constexpr int DX = 32;               // d_x
constexpr int DY = 16;               // d_y
constexpr int BB = 16;               // batch rows per block

// LDS strides in ushort units (16B-aligned rows, padded against bank conflicts)
constexpr int XROW  = 40;            // 80 B per x row (32 bf16 + pad)
constexpr int XSLOT = 16 * XROW;
constexpr int YROW  = 24;            // 48 B per y row (16 bf16 + pad)
constexpr int YSLOT = 16 * YROW;
constexpr int HROW  = 264;           // 528 B per h row (256 bf16 + pad)

__device__ __forceinline__ short bfbits(float f) {
  return __builtin_bit_cast(short, (__bf16)f);   // hardware RNE convert
}
__device__ __forceinline__ float fast_tanh(float a) {
  float e = __expf(2.0f * a);                    // stable both tails
  return 1.0f - 2.0f * __builtin_amdgcn_rcpf(e + 1.0f);
}
__device__ __forceinline__ float fast_sigmoid(float a) {
  return __builtin_amdgcn_rcpf(1.0f + __expf(-a));
}

__global__ __launch_bounds__(512, 2) void narx_kernel(
    const float* __restrict__ x,  const float* __restrict__ W1,
    const float* __restrict__ b1, const float* __restrict__ W2,
    const float* __restrict__ b2, float* __restrict__ out)
{
  __shared__ __align__(16) short xbuf[8 * XSLOT];   // 10240 B
  __shared__ __align__(16) short ybuf[8 * YSLOT];   //  6144 B
  __shared__ __align__(16) short hbuf[16 * HROW];   //  8448 B

  const int tid  = threadIdx.x;
  const int lane = tid & 63;
  const int w    = tid >> 6;        // wave 0..7 -> hidden cols [w*32, w*32+32)
  const int lm   = lane & 15;
  const int lg   = lane >> 4;       // 0..3
  const int b0   = blockIdx.x * BB;

  // ---- W1 fragments -> registers. B-frag of mfma(A,B): lane holds
  // W1[n = tile_base + lm][k = c*32 + lg*8 .. +7]. ----
  bf16x8 wf[2][12];
#pragma unroll
  for (int ti = 0; ti < 2; ++ti) {
    const int n = w * 32 + ti * 16 + lm;
#pragma unroll
    for (int c = 0; c < 12; ++c) {
      const float* p = W1 + n * 384 + c * 32 + lg * 8;
      bf16x8 v;
#pragma unroll
      for (int j = 0; j < 8; ++j) v[j] = bfbits(p[j]);
      wf[ti][c] = v;
    }
  }
  // W2 fragments: lane holds W2[y = lm][j = c*32 + lg*8 .. +7]
  bf16x8 w2f[8];
#pragma unroll
  for (int c = 0; c < 8; ++c) {
    const float* p = W2 + lm * 256 + c * 32 + lg * 8;
    bf16x8 v;
#pragma unroll
    for (int j = 0; j < 8; ++j) v[j] = bfbits(p[j]);
    w2f[c] = v;
  }
  const float b1v0 = b1[w * 32 + lm];
  const float b1v1 = b1[w * 32 + 16 + lm];
  const float b2v  = b2[lm];

  // ---- zero out[:, 0:8, :] for this block's rows (d_out is poisoned) ----
  {
    const int m = tid >> 5, off = (tid & 31) * 4;   // 128 floats per row prefix
    f32x4 z = {0.f, 0.f, 0.f, 0.f};
    *reinterpret_cast<f32x4*>(out + (size_t)(b0 + m) * (DT * DY) + off) = z;
  }

  // ---- preload x[0..7] window; zero y history ----
  {
    const int m = tid >> 5, k = tid & 31;
#pragma unroll
    for (int tt = 0; tt < 8; ++tt)
      xbuf[tt * XSLOT + m * XROW + k] =
          bfbits(x[(size_t)(b0 + m) * (DT * DX) + tt * DX + k]);
    for (int i = tid; i < 8 * YSLOT; i += 512) ybuf[i] = 0;
  }
  __syncthreads();

  const int pm = tid >> 5, pk = tid & 31;

  for (int t = 8; t < DT; ++t) {
    // prefetch x[t] (installed into the window at end of this step)
    const float xv = x[(size_t)(b0 + pm) * (DT * DX) + t * DX + pk];

    // ---- layer 1: inp[16,384] @ W1^T -> h[16,256] ----
    // A-frag: lane holds inp[m = lm][k = c*32 + lg*8 .. +7]
    bf16x8 af[12];
#pragma unroll
    for (int c = 0; c < 8; ++c) {               // x part: slot holds x[t-8+c]
      const int slot = (t + c) & 7;
      af[c] = *reinterpret_cast<const bf16x8*>(
          &xbuf[slot * XSLOT + lm * XROW + lg * 8]);
    }
#pragma unroll
    for (int c = 0; c < 4; ++c) {               // history part
      const int i    = c * 2 + (lg >> 1);       // history index 0..7
      const int slot = (t + i) & 7;             // holds y[t-8+i]
      af[8 + c] = *reinterpret_cast<const bf16x8*>(
          &ybuf[slot * YSLOT + lm * YROW + (lg & 1) * 8]);
    }
    // 4 independent 6-deep MFMA chains per wave (8 chains/SIMD at 2 waves) --
    // enough ILP to hide MFMA latency; fp32 halves summed before tanh.
    f32x4 acc0a = {0.f, 0.f, 0.f, 0.f}, acc0b = {0.f, 0.f, 0.f, 0.f};
    f32x4 acc1a = {0.f, 0.f, 0.f, 0.f}, acc1b = {0.f, 0.f, 0.f, 0.f};
#pragma unroll
    for (int c = 0; c < 6; ++c) {
      acc0a = MFMA16(af[c],     wf[0][c],     acc0a);
      acc1a = MFMA16(af[c],     wf[1][c],     acc1a);
      acc0b = MFMA16(af[c + 6], wf[0][c + 6], acc0b);
      acc1b = MFMA16(af[c + 6], wf[1][c + 6], acc1b);
    }
    // tanh + stage h to LDS (row = batch m; padded stride kills bank conflicts)
#pragma unroll
    for (int r = 0; r < 4; ++r) {
      const int row = lg * 4 + r;               // D-frag: row=(lane>>4)*4+reg, col=lane&15
      const float h0 = fast_tanh(acc0a[r] + acc0b[r] + b1v0);
      const float h1 = fast_tanh(acc1a[r] + acc1b[r] + b1v1);
      hbuf[row * HROW + w * 32 + lm]      = bfbits(h0);
      hbuf[row * HROW + w * 32 + 16 + lm] = bfbits(h1);
    }
    __syncthreads();

    // ---- layer 2 (waves 0,1 compute redundantly; others skip to barrier) ----
    if (w < 2) {
      f32x4 a2 = {0.f, 0.f, 0.f, 0.f};
      f32x4 a3 = {0.f, 0.f, 0.f, 0.f};
#pragma unroll
      for (int c = 0; c < 4; ++c) {             // two interleaved 4-deep chains
        bf16x8 hf0 = *reinterpret_cast<const bf16x8*>(
            &hbuf[lm * HROW + (2 * c) * 32 + lg * 8]);
        bf16x8 hf1 = *reinterpret_cast<const bf16x8*>(
            &hbuf[lm * HROW + (2 * c + 1) * 32 + lg * 8]);
        a2 = MFMA16(hf0, w2f[2 * c],     a2);
        a3 = MFMA16(hf1, w2f[2 * c + 1], a3);
      }
#pragma unroll
      for (int r = 0; r < 4; ++r) {
        const float o = fast_sigmoid(a2[r] + a3[r] + b2v);
        if (w == 0) {  // feed back: slot t&7 held y[t-8], dead after this step's reads
          ybuf[(t & 7) * YSLOT + (lg * 4 + r) * YROW + lm] = bfbits(o);
        } else {       // wave 1 writes the fp32 output
          out[(size_t)(b0 + lg * 4 + r) * (DT * DY) + t * DY + lm] = o;
        }
      }
    }
    // rotate x window: slot t&7 (x[t-8], dead after layer-1 reads) := x[t]
    xbuf[(t & 7) * XSLOT + pm * XROW + pk] = bfbits(xv);
    __syncthreads();
  }
}

extern "C" void kernel_launch(void* const* d_in, const int* in_sizes, int n_in,
                              void* d_out, int out_size, void* d_ws, size_t ws_size,
                              hipStream_t stream) {
  const float* x  = (const float*)d_in[0];
  const float* W1 = (const float*)d_in[1];
  const float* b1 = (const float*)d_in[2];
  const float* W2 = (const float*)d_in[3];
  const float* b2 = (const float*)d_in[4];
  float* out = (float*)d_out;
  narx_kernel<<<dim3(128), dim3(512), 0, stream>>>(x, W1, b1, W2, b2, out);
}

// Round 6
// 765.587 us; speedup vs baseline: 1.0467x; 1.0467x over previous
//
#include <hip/hip_runtime.h>
#include <hip/hip_bf16.h>

// Closed-loop NARX on MI355X.
// 128 blocks x 512 threads (8 waves); each block owns 16 batch rows for all
// 504 steps. W1 fragments register-resident. Layer 2 is K-split across all
// 8 waves (1 MFMA each over its own 32 h-columns) + LDS partial reduction,
// so no cross-wave h reads and no 2-wave serial tail.

typedef short bf16x8 __attribute__((ext_vector_type(8)));  // 8 bf16 bit patterns
typedef float f32x4  __attribute__((ext_vector_type(4)));

#define MFMA16(A,B,C) __builtin_amdgcn_mfma_f32_16x16x32_bf16((A),(B),(C),0,0,0)

constexpr int DT = 512;              // T
constexpr int DX = 32;               // d_x
constexpr int DY = 16;               // d_y
constexpr int BB = 16;               // batch rows per block

// LDS strides in ushort units (16B-aligned rows)
constexpr int XROW  = 40;            // 80 B per x row (32 bf16 + pad)
constexpr int XSLOT = 16 * XROW;
constexpr int YROW  = 24;            // 48 B per y row (16 bf16 + pad)
constexpr int YSLOT = 16 * YROW;
constexpr int HROW  = 264;           // 528 B per h row (256 bf16 + pad)
constexpr int PROW  = 17;            // f32 partial row stride (pad kills lg conflicts)
constexpr int PWAVE = 16 * PROW;     // 272 f32 per wave

__device__ __forceinline__ short bfbits(float f) {
  return __builtin_bit_cast(short, (__bf16)f);   // hardware RNE convert
}
__device__ __forceinline__ float fast_tanh(float a) {
  float e = __expf(2.0f * a);                    // stable both tails
  return 1.0f - 2.0f * __builtin_amdgcn_rcpf(e + 1.0f);
}
__device__ __forceinline__ float fast_sigmoid(float a) {
  return __builtin_amdgcn_rcpf(1.0f + __expf(-a));
}

__global__ __launch_bounds__(512, 2) void narx_kernel(
    const float* __restrict__ x,  const float* __restrict__ W1,
    const float* __restrict__ b1, const float* __restrict__ W2,
    const float* __restrict__ b2, float* __restrict__ out)
{
  __shared__ __align__(16) short xbuf[8 * XSLOT];   // 10240 B
  __shared__ __align__(16) short ybuf[8 * YSLOT];   //  6144 B
  __shared__ __align__(16) short hbuf[16 * HROW];   //  8448 B
  __shared__ __align__(16) float pbuf[8 * PWAVE];   //  8704 B

  const int tid  = threadIdx.x;
  const int lane = tid & 63;
  const int w    = tid >> 6;        // wave 0..7 -> hidden cols [w*32, w*32+32)
  const int lm   = lane & 15;
  const int lg   = lane >> 4;       // 0..3
  const int b0   = blockIdx.x * BB;

  // ---- W1 fragments -> registers. B-frag: lane holds W1[n=base+lm][k=c*32+lg*8..+7]
  bf16x8 wf[2][12];
#pragma unroll
  for (int ti = 0; ti < 2; ++ti) {
    const int n = w * 32 + ti * 16 + lm;
#pragma unroll
    for (int c = 0; c < 12; ++c) {
      const float* p = W1 + n * 384 + c * 32 + lg * 8;
      bf16x8 v;
#pragma unroll
      for (int j = 0; j < 8; ++j) v[j] = bfbits(p[j]);
      wf[ti][c] = v;
    }
  }
  // W2 K-slice for this wave: lane holds W2[n=lm][k = w*32 + lg*8 .. +7]
  bf16x8 w2fp;
  {
    const float* p = W2 + lm * 256 + w * 32 + lg * 8;
    bf16x8 v;
#pragma unroll
    for (int j = 0; j < 8; ++j) v[j] = bfbits(p[j]);
    w2fp = v;
  }
  const float b1v0 = b1[w * 32 + lm];
  const float b1v1 = b1[w * 32 + 16 + lm];
  const float b2v  = b2[lm];

  // ---- zero out[:, 0:8, :] for this block's rows (d_out is poisoned) ----
  {
    const int m = tid >> 5, off = (tid & 31) * 4;   // 128 floats per row prefix
    f32x4 z = {0.f, 0.f, 0.f, 0.f};
    *reinterpret_cast<f32x4*>(out + (size_t)(b0 + m) * (DT * DY) + off) = z;
  }

  // ---- preload x[0..7] window; zero y history ----
  {
    const int m = tid >> 5, k = tid & 31;
#pragma unroll
    for (int tt = 0; tt < 8; ++tt)
      xbuf[tt * XSLOT + m * XROW + k] =
          bfbits(x[(size_t)(b0 + m) * (DT * DX) + tt * DX + k]);
    for (int i = tid; i < 8 * YSLOT; i += 512) ybuf[i] = 0;
  }
  __syncthreads();

  const int pm = tid >> 5, pk = tid & 31;

  for (int t = 8; t < DT; ++t) {
    // prefetch x[t] (installed into the window after barrier 1)
    const float xv = x[(size_t)(b0 + pm) * (DT * DX) + t * DX + pk];

    // ---- layer 1: inp[16,384] @ W1^T -> h[16,256] (wave owns 32 cols) ----
    bf16x8 af[12];
#pragma unroll
    for (int c = 0; c < 8; ++c) {               // x part: slot holds x[t-8+c]
      const int slot = (t + c) & 7;
      af[c] = *reinterpret_cast<const bf16x8*>(
          &xbuf[slot * XSLOT + lm * XROW + lg * 8]);
    }
#pragma unroll
    for (int c = 0; c < 4; ++c) {               // history part
      const int i    = c * 2 + (lg >> 1);       // history index 0..7
      const int slot = (t + i) & 7;             // holds y[t-8+i]
      af[8 + c] = *reinterpret_cast<const bf16x8*>(
          &ybuf[slot * YSLOT + lm * YROW + (lg & 1) * 8]);
    }
    // 4 independent 6-deep MFMA chains per wave (8 chains/SIMD at 2 waves)
    f32x4 acc0a = {0.f, 0.f, 0.f, 0.f}, acc0b = {0.f, 0.f, 0.f, 0.f};
    f32x4 acc1a = {0.f, 0.f, 0.f, 0.f}, acc1b = {0.f, 0.f, 0.f, 0.f};
#pragma unroll
    for (int c = 0; c < 6; ++c) {
      acc0a = MFMA16(af[c],     wf[0][c],     acc0a);
      acc1a = MFMA16(af[c],     wf[1][c],     acc1a);
      acc0b = MFMA16(af[c + 6], wf[0][c + 6], acc0b);
      acc1b = MFMA16(af[c + 6], wf[1][c + 6], acc1b);
    }
    // tanh + stage this wave's h slice to LDS (only re-read by the same wave)
#pragma unroll
    for (int r = 0; r < 4; ++r) {
      const int row = lg * 4 + r;               // D-frag: row=(lane>>4)*4+reg, col=lane&15
      const float h0 = fast_tanh(acc0a[r] + acc0b[r] + b1v0);
      const float h1 = fast_tanh(acc1a[r] + acc1b[r] + b1v1);
      hbuf[row * HROW + w * 32 + lm]      = bfbits(h0);
      hbuf[row * HROW + w * 32 + 16 + lm] = bfbits(h1);
    }

    // ---- layer 2, K-split: 1 MFMA per wave over its own 32 h-columns ----
    // A-frag: lane holds h[m=lm][k = w*32 + lg*8 .. +7] (written by this wave)
    bf16x8 ha = *reinterpret_cast<const bf16x8*>(
        &hbuf[lm * HROW + w * 32 + lg * 8]);
    f32x4 zero = {0.f, 0.f, 0.f, 0.f};
    f32x4 part = MFMA16(ha, w2fp, zero);
#pragma unroll
    for (int r = 0; r < 4; ++r)
      pbuf[w * PWAVE + (lg * 4 + r) * PROW + lm] = part[r];
    __syncthreads();                            // barrier 1: partials visible

    // ---- reduce 8 partials + sigmoid (waves 0-3; one y element per thread) ----
    if (tid < 256) {
      const int row = tid >> 4, col = tid & 15; // col == lm for these threads
      float s = b2v;
#pragma unroll
      for (int ww = 0; ww < 8; ++ww)
        s += pbuf[ww * PWAVE + row * PROW + col];
      const float o = fast_sigmoid(s);
      ybuf[(t & 7) * YSLOT + row * YROW + col] = bfbits(o);   // feed back
      out[(size_t)(b0 + row) * (DT * DY) + t * DY + col] = o; // fp32 output
    }
    // rotate x window: slot t&7 (x[t-8], dead after this step's af reads) := x[t]
    xbuf[(t & 7) * XSLOT + pm * XROW + pk] = bfbits(xv);
    __syncthreads();                            // barrier 2: y/x ready for t+1
  }
}

extern "C" void kernel_launch(void* const* d_in, const int* in_sizes, int n_in,
                              void* d_out, int out_size, void* d_ws, size_t ws_size,
                              hipStream_t stream) {
  const float* x  = (const float*)d_in[0];
  const float* W1 = (const float*)d_in[1];
  const float* b1 = (const float*)d_in[2];
  const float* W2 = (const float*)d_in[3];
  const float* b2 = (const float*)d_in[4];
  float* out = (float*)d_out;
  narx_kernel<<<dim3(128), dim3(512), 0, stream>>>(x, W1, b1, W2, b2, out);
}

// Round 9
// 649.933 us; speedup vs baseline: 1.2330x; 1.1779x over previous
//
#include <hip/hip_runtime.h>
#include <hip/hip_bf16.h>

// Closed-loop NARX on MI355X.
// 128 blocks x 512 threads (8 waves); each block owns 16 batch rows for all
// 504 steps. W1/W2 fragments AND the 8-slot x-window are register-resident;
// the t-loop is unrolled by 8 so the circular slot indices are static and the
// weight<->slot pairing rotates instead of the data. LDS holds only the
// y history, the per-wave h tile (XOR-swizzled), and f32 layer-2 partials.

typedef short bf16x8 __attribute__((ext_vector_type(8)));  // 8 bf16 bit patterns
typedef float f32x4  __attribute__((ext_vector_type(4)));

#define MFMA16(A,B,C) __builtin_amdgcn_mfma_f32_16x16x32_bf16((A),(B),(C),0,0,0)

constexpr int DT = 512;              // T
constexpr int DX = 32;               // d_x
constexpr int DY = 16;               // d_y
constexpr int BB = 16;               // batch rows per block

// LDS strides (ushort units unless noted)
constexpr int YROW  = 24;            // 48 B per y row
constexpr int YSLOT = 16 * YROW;     // 384
constexpr int HROW  = 40;            // 80 B per h row (32 bf16 + pad)
constexpr int HWAVE = 16 * HROW;     // per-wave h tile (640 shorts)
constexpr int PROW  = 18;            // f32 partial row stride (2-way max = free)
constexpr int PWAVE = 16 * PROW;     // 288 f32 per wave

__device__ __forceinline__ short bfbits(float f) {
  return __builtin_bit_cast(short, (__bf16)f);   // hardware RNE convert
}
__device__ __forceinline__ float fast_tanh(float a) {
  float e = __expf(2.0f * a);                    // stable both tails
  return 1.0f - 2.0f * __builtin_amdgcn_rcpf(e + 1.0f);
}
__device__ __forceinline__ float fast_sigmoid(float a) {
  return __builtin_amdgcn_rcpf(1.0f + __expf(-a));
}

__global__ __launch_bounds__(512, 2) void narx_kernel(
    const float* __restrict__ x,  const float* __restrict__ W1,
    const float* __restrict__ b1, const float* __restrict__ W2,
    const float* __restrict__ b2, float* __restrict__ out)
{
  __shared__ __align__(16) short ybuf[8 * YSLOT];   //  6144 B
  __shared__ __align__(16) short hbuf[8 * HWAVE];   // 10240 B
  __shared__ __align__(16) float pbuf[8 * PWAVE];   //  9216 B

  const int tid  = threadIdx.x;
  const int lane = tid & 63;
  const int w    = tid >> 6;        // wave 0..7 -> hidden cols [w*32, w*32+32)
  const int lm   = lane & 15;
  const int lg   = lane >> 4;       // 0..3
  const int b0   = blockIdx.x * BB;

  // ---- W1 fragments: lane holds W1[n=base+lm][k = c*32 + lg*8 .. +7] ----
  bf16x8 wf[2][12];
#pragma unroll
  for (int ti = 0; ti < 2; ++ti) {
    const int n = w * 32 + ti * 16 + lm;
#pragma unroll
    for (int c = 0; c < 12; ++c) {
      const float* p = W1 + n * 384 + c * 32 + lg * 8;
      bf16x8 v;
#pragma unroll
      for (int j = 0; j < 8; ++j) v[j] = bfbits(p[j]);
      wf[ti][c] = v;
    }
  }
  // W2 K-slice for this wave: lane holds W2[n=lm][k = w*32 + lg*8 .. +7]
  bf16x8 w2fp;
  {
    const float* p = W2 + lm * 256 + w * 32 + lg * 8;
    bf16x8 v;
#pragma unroll
    for (int j = 0; j < 8; ++j) v[j] = bfbits(p[j]);
    w2fp = v;
  }
  const float b1v0 = b1[w * 32 + lm];
  const float b1v1 = b1[w * 32 + 16 + lm];
  const float b2v  = b2[lm];

  // ---- zero out[:, 0:8, :] for this block's rows (d_out is poisoned) ----
  {
    const int m = tid >> 5, off = (tid & 31) * 4;   // 128 floats per row prefix
    f32x4 z = {0.f, 0.f, 0.f, 0.f};
    *reinterpret_cast<f32x4*>(out + (size_t)(b0 + m) * (DT * DY) + off) = z;
  }

  // ---- register-resident x window: slot s holds x[tau], tau%8 == s ----
  const float* xlane = x + (size_t)(b0 + lm) * (DT * DX) + lg * 8;
  bf16x8 xr[8];
#pragma unroll
  for (int s = 0; s < 8; ++s) {
    f32x4 a = *reinterpret_cast<const f32x4*>(xlane + s * DX);
    f32x4 b = *reinterpret_cast<const f32x4*>(xlane + s * DX + 4);
    bf16x8 v;
#pragma unroll
    for (int j = 0; j < 4; ++j) { v[j] = bfbits(a[j]); v[4 + j] = bfbits(b[j]); }
    xr[s] = v;
  }
  // prefetch x[8] (consumed as CUR at the first step)
  f32x4 gA0 = *reinterpret_cast<const f32x4*>(xlane + 8 * DX);
  f32x4 gA1 = *reinterpret_cast<const f32x4*>(xlane + 8 * DX + 4);
  f32x4 gB0 = gA0, gB1 = gA1;

  // zero y history
  for (int i = tid; i < 8 * YSLOT; i += 512) ybuf[i] = 0;
  __syncthreads();

  // precomputed lane constants
  const int yhalf  = lg >> 1;                    // y history index parity
  const int yoff   = lm * YROW + (lg & 1) * 8;   // + slot*YSLOT per read
  const int hw_w   = w * HWAVE;
  const int hswz_w = lg << 3;                    // write swizzle (row>>2 == lg)
  const int hread  = hw_w + ((lm * HROW + lg * 8) ^ (((lm >> 2) & 3) << 3));
  const int pw     = w * PWAVE;
  const int rrow   = tid >> 4, rcol = tid & 15;  // reduce thread mapping

#define STEP(U, CUR0, CUR1, NXT0, NXT1)                                        \
  do {                                                                         \
    const int t = tb + (U);                                                    \
    { const int tl = (t + 1 < DT) ? (t + 1) : (DT - 1);                        \
      NXT0 = *reinterpret_cast<const f32x4*>(xlane + tl * DX);                 \
      NXT1 = *reinterpret_cast<const f32x4*>(xlane + tl * DX + 4); }           \
    bf16x8 ay0, ay1, ay2, ay3;                                                 \
    ay0 = *reinterpret_cast<const bf16x8*>(                                    \
        &ybuf[((((U) + 0 + yhalf) & 7) * YSLOT) + yoff]);                      \
    ay1 = *reinterpret_cast<const bf16x8*>(                                    \
        &ybuf[((((U) + 2 + yhalf) & 7) * YSLOT) + yoff]);                      \
    ay2 = *reinterpret_cast<const bf16x8*>(                                    \
        &ybuf[((((U) + 4 + yhalf) & 7) * YSLOT) + yoff]);                      \
    ay3 = *reinterpret_cast<const bf16x8*>(                                    \
        &ybuf[((((U) + 6 + yhalf) & 7) * YSLOT) + yoff]);                      \
    f32x4 acc0a = {0.f,0.f,0.f,0.f}, acc0b = {0.f,0.f,0.f,0.f};                \
    f32x4 acc1a = {0.f,0.f,0.f,0.f}, acc1b = {0.f,0.f,0.f,0.f};                \
    _Pragma("unroll") for (int c = 0; c < 6; ++c) {                            \
      acc0a = MFMA16(xr[((U) + c) & 7], wf[0][c], acc0a);                      \
      acc1a = MFMA16(xr[((U) + c) & 7], wf[1][c], acc1a);                      \
    }                                                                          \
    acc0b = MFMA16(xr[((U) + 6) & 7], wf[0][6], acc0b);                        \
    acc1b = MFMA16(xr[((U) + 6) & 7], wf[1][6], acc1b);                        \
    acc0b = MFMA16(xr[((U) + 7) & 7], wf[0][7], acc0b);                        \
    acc1b = MFMA16(xr[((U) + 7) & 7], wf[1][7], acc1b);                        \
    acc0b = MFMA16(ay0, wf[0][8],  acc0b);  acc1b = MFMA16(ay0, wf[1][8],  acc1b); \
    acc0b = MFMA16(ay1, wf[0][9],  acc0b);  acc1b = MFMA16(ay1, wf[1][9],  acc1b); \
    acc0b = MFMA16(ay2, wf[0][10], acc0b);  acc1b = MFMA16(ay2, wf[1][10], acc1b); \
    acc0b = MFMA16(ay3, wf[0][11], acc0b);  acc1b = MFMA16(ay3, wf[1][11], acc1b); \
    { bf16x8 nx;                                                               \
      _Pragma("unroll") for (int j = 0; j < 4; ++j) {                          \
        nx[j] = bfbits(CUR0[j]); nx[4 + j] = bfbits(CUR1[j]); }                \
      xr[(U) & 7] = nx; }                                                      \
    _Pragma("unroll") for (int r = 0; r < 4; ++r) {                            \
      const int row = lg * 4 + r;                                              \
      const float h0 = fast_tanh(acc0a[r] + acc0b[r] + b1v0);                  \
      const float h1 = fast_tanh(acc1a[r] + acc1b[r] + b1v1);                  \
      hbuf[hw_w + ((row * HROW + lm) ^ hswz_w)]      = bfbits(h0);             \
      hbuf[hw_w + ((row * HROW + 16 + lm) ^ hswz_w)] = bfbits(h1);             \
    }                                                                          \
    bf16x8 ha = *reinterpret_cast<const bf16x8*>(&hbuf[hread]);                \
    f32x4 pz = {0.f, 0.f, 0.f, 0.f};                                           \
    f32x4 part = MFMA16(ha, w2fp, pz);                                         \
    _Pragma("unroll") for (int r = 0; r < 4; ++r)                              \
      pbuf[pw + (lg * 4 + r) * PROW + lm] = part[r];                           \
    __syncthreads();                                                           \
    if (tid < 256) {                                                           \
      float s = b2v;                                                           \
      _Pragma("unroll") for (int ww = 0; ww < 8; ++ww)                         \
        s += pbuf[ww * PWAVE + rrow * PROW + rcol];                            \
      const float o = fast_sigmoid(s);                                         \
      ybuf[((U) & 7) * YSLOT + rrow * YROW + rcol] = bfbits(o);                \
      out[(size_t)(b0 + rrow) * (DT * DY) + t * DY + rcol] = o;                \
    }                                                                          \
    __syncthreads();                                                           \
  } while (0)

  for (int tb = 8; tb < DT; tb += 8) {   // 504 steps = 63 x 8, all slots static
    STEP(0, gA0, gA1, gB0, gB1);
    STEP(1, gB0, gB1, gA0, gA1);
    STEP(2, gA0, gA1, gB0, gB1);
    STEP(3, gB0, gB1, gA0, gA1);
    STEP(4, gA0, gA1, gB0, gB1);
    STEP(5, gB0, gB1, gA0, gA1);
    STEP(6, gA0, gA1, gB0, gB1);
    STEP(7, gB0, gB1, gA0, gA1);
  }
#undef STEP
}

extern "C" void kernel_launch(void* const* d_in, const int* in_sizes, int n_in,
                              void* d_out, int out_size, void* d_ws, size_t ws_size,
                              hipStream_t stream) {
  const float* x  = (const float*)d_in[0];
  const float* W1 = (const float*)d_in[1];
  const float* b1 = (const float*)d_in[2];
  const float* W2 = (const float*)d_in[3];
  const float* b2 = (const float*)d_in[4];
  float* out = (float*)d_out;
  narx_kernel<<<dim3(128), dim3(512), 0, stream>>>(x, W1, b1, W2, b2, out);
}